// Round 9
// baseline (43.189 us; speedup 1.0000x reference)
//
#include <hip/hip_runtime.h>
#include <math.h>

#define BATCH 32
#define H 512
#define W 512
#define PAD 15
#define INV_KK (1.0f / 961.0f)

#define YSEG 32
#define NSEG (H / YSEG)                 /* 16 */
#define NB1 (BATCH * NSEG * W / 256)    /* 1024 blocks for K1 */

#define RG 4                            /* rows per wave in K2 */
#define GRPS (H / RG)                   /* 128 */
#define NWAVES2 (BATCH * GRPS)          /* 4096 */
#define WPB 4
#define NB2 (NWAVES2 / WPB)             /* 1024 */
#define NXCD 8

/* ================= K1: vertical 31-row sliding sums, thread = column ===== */
__global__ __launch_bounds__(256)
void vpool_kernel(const float* __restrict__ t, float* __restrict__ V) {
    const int bid  = (int)blockIdx.x;
    const int sbid = (bid & (NXCD - 1)) * (NB1 / NXCD) + (bid >> 3);
    const int gid  = sbid * 256 + (int)threadIdx.x;
    const int col  = gid & (W - 1);
    const int seg  = (gid >> 9) & (NSEG - 1);
    const int img  = gid >> 13;
    const float* tc = t + (size_t)img * H * W + col;
    float*       vc = V + (size_t)img * H * W + col;
    const int y0 = seg * YSEG;

    float run = 0.f;
    if (seg >= 1 && seg <= NSEG - 2) {          /* interior: no guards */
        #pragma unroll
        for (int d = -PAD; d <= PAD; ++d) run += tc[(y0 + d) * W];
        #pragma unroll
        for (int j = 0; j < YSEG; ++j) {
            vc[(y0 + j) * W] = run;
            run += tc[(y0 + j + PAD + 1) * W] - tc[(y0 + j - PAD) * W];
        }
    } else {
        #pragma unroll
        for (int d = -PAD; d <= PAD; ++d) {
            int y = y0 + d;
            if ((unsigned)y < (unsigned)H) run += tc[y * W];
        }
        #pragma unroll
        for (int j = 0; j < YSEG; ++j) {
            vc[(y0 + j) * W] = run;
            int ye = y0 + j + PAD + 1, yl = y0 + j - PAD;
            float ev = ((unsigned)ye < (unsigned)H) ? tc[ye * W] : 0.f;
            float lv = ((unsigned)yl < (unsigned)H) ? tc[yl * W] : 0.f;
            run += ev - lv;
        }
    }
}

/* ================= K2: horizontal window + fused weight/BCE ============== */
/* fused weight + stable BCE for one element */
#define EMIT(tv, lv, hs)                                                      \
    {                                                                         \
        float pooled_ = (hs) * INV_KK;                                        \
        float wgt_ = fmaf(5.f, fabsf(pooled_ - (tv)), 1.f);                   \
        float al_ = fabsf(lv);                                                \
        float bce_ = fmaxf((lv), 0.f) - (lv) * (tv)                           \
                     + __logf(1.f + __expf(-al_));                            \
        num = fmaf(wgt_, bce_, num);                                          \
        den += wgt_;                                                          \
    }

/* one k-slot of the horizontal 31-window (verified bit-exact R7/R8) */
#define KSLOT(pk, pkm1, tv, lv, FIRST, LAST)                                  \
    {                                                                         \
        float hs_ = base_;                                                    \
        if (!(LAST)) {                                                        \
            float sa_ = __shfl_up(tot_ - (pk), 2);                            \
            hs_ += okm2 ? sa_ : 0.f;                                          \
        }                                                                     \
        if (!(FIRST)) {                                                       \
            float se_ = __shfl_down((pkm1), 2);                               \
            hs_ += okp2 ? se_ : 0.f;                                          \
        }                                                                     \
        EMIT(tv, lv, hs_)                                                     \
    }

#define ROW_EMIT(va, vb, t0_, t1_, l0_, l1_)                                  \
    {                                                                         \
        const float p0_ = (va).x;                                             \
        const float p1_ = p0_ + (va).y;                                       \
        const float p2_ = p1_ + (va).z;                                       \
        const float p3_ = p2_ + (va).w;                                       \
        const float p4_ = p3_ + (vb).x;                                       \
        const float p5_ = p4_ + (vb).y;                                       \
        const float p6_ = p5_ + (vb).z;                                       \
        const float tot_ = p6_ + (vb).w;                                      \
        const float bm_ = __shfl_up(tot_, 1);                                 \
        const float dp_ = __shfl_down(tot_, 1);                               \
        const float base_ = (okm1 ? bm_ : 0.f) + tot_ + (okp1 ? dp_ : 0.f);   \
        KSLOT(p0_, 0.f, (t0_).x, (l0_).x, 1, 0)                               \
        KSLOT(p1_, p0_, (t0_).y, (l0_).y, 0, 0)                               \
        KSLOT(p2_, p1_, (t0_).z, (l0_).z, 0, 0)                               \
        KSLOT(p3_, p2_, (t0_).w, (l0_).w, 0, 0)                               \
        KSLOT(p4_, p3_, (t1_).x, (l1_).x, 0, 0)                               \
        KSLOT(p5_, p4_, (t1_).y, (l1_).y, 0, 0)                               \
        KSLOT(p6_, p5_, (t1_).z, (l1_).z, 0, 0)                               \
        KSLOT(0.f, p6_, (t1_).w, (l1_).w, 0, 1)                               \
    }

#define LD(pa, pb, ptr, yy)                                                   \
    { const float4* p_ = (const float4*)((ptr) + (size_t)(yy) * W + x0);      \
      pa = p_[0]; pb = p_[1]; }

__global__ __launch_bounds__(WPB * 64)
void hbce_kernel(const float* __restrict__ logits,
                 const float* __restrict__ targets,
                 const float* __restrict__ V,
                 float* __restrict__ partials) {
    __shared__ float rn[WPB], rd[WPB];

    const int tid  = threadIdx.x;
    const int lane = tid & 63;
    const int w    = tid >> 6;
    const int bid  = (int)blockIdx.x;
    const int sbid = (bid & (NXCD - 1)) * (NB2 / NXCD) + (bid >> 3);
    const int wid  = sbid * WPB + w;
    const int img  = wid >> 7;
    const int grp  = wid & (GRPS - 1);
    const int y0   = grp * RG;
    const int x0   = lane * 8;

    const size_t ibase = (size_t)img * H * W;
    const float* tb = targets + ibase;
    const float* lb = logits  + ibase;
    const float* vp = V       + ibase;

    /* prefetch ALL rows (24 independent float4 loads, one drain) */
    float4 V0a, V0b, V1a, V1b, V2a, V2b, V3a, V3b;
    float4 T0a, T0b, T1a, T1b, T2a, T2b, T3a, T3b;
    float4 L0a, L0b, L1a, L1b, L2a, L2b, L3a, L3b;
    LD(V0a, V0b, vp, y0 + 0) LD(V1a, V1b, vp, y0 + 1)
    LD(V2a, V2b, vp, y0 + 2) LD(V3a, V3b, vp, y0 + 3)
    LD(T0a, T0b, tb, y0 + 0) LD(T1a, T1b, tb, y0 + 1)
    LD(T2a, T2b, tb, y0 + 2) LD(T3a, T3b, tb, y0 + 3)
    LD(L0a, L0b, lb, y0 + 0) LD(L1a, L1b, lb, y0 + 1)
    LD(L2a, L2b, lb, y0 + 2) LD(L3a, L3b, lb, y0 + 3)

    const bool okm2 = lane >= 2, okm1 = lane >= 1;
    const bool okp1 = lane <= 62, okp2 = lane <= 61;
    float num = 0.f, den = 0.f;

    ROW_EMIT(V0a, V0b, T0a, T0b, L0a, L0b)
    ROW_EMIT(V1a, V1b, T1a, T1b, L1a, L1b)
    ROW_EMIT(V2a, V2b, T2a, T2b, L2a, L2b)
    ROW_EMIT(V3a, V3b, T3a, T3b, L3a, L3b)

    /* ---- wave + block reduction, one partial pair per block ---- */
    #pragma unroll
    for (int off = 32; off > 0; off >>= 1) {
        num += __shfl_down(num, off);
        den += __shfl_down(den, off);
    }
    if (lane == 0) { rn[w] = num; rd[w] = den; }
    __syncthreads();
    if (tid == 0) {
        float n = 0.f, d = 0.f;
        #pragma unroll
        for (int i = 0; i < WPB; ++i) { n += rn[i]; d += rd[i]; }
        partials[sbid * 2]     = n;
        partials[sbid * 2 + 1] = d;
    }
}

/* 1024 partial pairs -> scalar. Image i owns pairs [i*32, i*32+32). */
__global__ __launch_bounds__(1024)
void wbce_finalize_kernel(const float* __restrict__ partials,
                          float* __restrict__ out) {
    __shared__ float rsum[16];
    const int t = threadIdx.x;
    float num = partials[t * 2];
    float den = partials[t * 2 + 1];
    #pragma unroll
    for (int off = 16; off > 0; off >>= 1) {
        num += __shfl_down(num, off, 32);
        den += __shfl_down(den, off, 32);
    }
    float ratio = 0.f;
    if ((t & 31) == 0) ratio = num / den;
    ratio += __shfl_down(ratio, 32);          /* lane0 += lane32 */
    const int lane = t & 63;
    const int wv = t >> 6;
    if (lane == 0) rsum[wv] = ratio;
    __syncthreads();
    if (t == 0) {
        float s = 0.f;
        #pragma unroll
        for (int i = 0; i < 16; ++i) s += rsum[i];
        out[0] = s / (float)BATCH;
    }
}

extern "C" void kernel_launch(void* const* d_in, const int* in_sizes, int n_in,
                              void* d_out, int out_size, void* d_ws, size_t ws_size,
                              hipStream_t stream) {
    const float* logits  = (const float*)d_in[0];
    const float* targets = (const float*)d_in[1];
    float* out = (float*)d_out;

    float* V        = (float*)d_ws;                 /* 32*512*512*4 = 33.5 MB */
    float* partials = (float*)((char*)d_ws + (size_t)BATCH * H * W * sizeof(float));

    vpool_kernel<<<NB1, 256, 0, stream>>>(targets, V);
    hbce_kernel<<<NB2, WPB * 64, 0, stream>>>(logits, targets, V, partials);
    wbce_finalize_kernel<<<1, 1024, 0, stream>>>(partials, out);
}